// Round 10
// baseline (87.913 us; speedup 1.0000x reference)
//
#include <hip/hip_runtime.h>
#include <hip/hip_bf16.h>

typedef _Float16 half8 __attribute__((ext_vector_type(8)));
typedef _Float16 half4v __attribute__((ext_vector_type(4)));
typedef _Float16 half2v __attribute__((ext_vector_type(2)));
typedef __fp16 pkh2 __attribute__((ext_vector_type(2)));
typedef float f32x4 __attribute__((ext_vector_type(4)));

static __device__ __forceinline__ f32x4 mfma16(half8 a, half8 b, f32x4 c) {
    return __builtin_amdgcn_mfma_f32_16x16x32_f16(a, b, c, 0, 0, 0);
}

typedef const __attribute__((address_space(1))) unsigned int* gas_ptr;
typedef __attribute__((address_space(3))) unsigned int* las_ptr;
static __device__ __forceinline__ void gload16(const void* g, void* l) {
    __builtin_amdgcn_global_load_lds((gas_ptr)g, (las_ptr)l, 16, 0, 0);
}

static __device__ __forceinline__ half2v cvt2(float a, float b) {
    pkh2 t = __builtin_amdgcn_cvt_pkrtz(a, b);
    return __builtin_bit_cast(half2v, t);
}
static __device__ __forceinline__ half8 pk8(f32x4 a, f32x4 b) {
    half2v x0 = cvt2(a[0], a[1]);
    half2v x1 = cvt2(a[2], a[3]);
    half2v x2 = cvt2(b[0], b[1]);
    half2v x3 = cvt2(b[2], b[3]);
    half4v lo = __builtin_shufflevector(x0, x1, 0, 1, 2, 3);
    half4v hi = __builtin_shufflevector(x2, x3, 0, 1, 2, 3);
    return __builtin_shufflevector(lo, hi, 0, 1, 2, 3, 4, 5, 6, 7);
}
static __device__ __forceinline__ half4v pk4(f32x4 a) {
    half2v x0 = cvt2(a[0], a[1]);
    half2v x1 = cvt2(a[2], a[3]);
    return __builtin_shufflevector(x0, x1, 0, 1, 2, 3);
}

// ---------------- workspace layout (bytes) ----------------
#define WS_APCONV   0u          // 147456
#define WS_APW2S    147456u     // 4096
#define WS_APCA     151552u     // 8192
#define WS_APW2K4   159744u     // 8192
#define WS_PACKED   196608u     // 8,652,800   [b][8][130][130][8] f16
#define WS_MASKQ    8849408u    // 1,048,576   [b][8][128][128] f16
#define WS_MASKK    10946560u   // 1,048,576
#define WS_Q16      13043712u   // 262,144     [b][4096][8] f16
#define WS_K16      13305856u   // 262,144
#define WS_V16      13568000u   // 2,097,152   [b][64][4096] f16 (tile-slot permuted)
#define WS_ZB       15665152u   // 2,097,152   [b][4096][64] f16 (small path only)
#define WS_PACC8    17762304u   // 16,777,216  [512 blocks][256 q][64 c] f16
#define WS_PML8     34539520u   // 524,288     [512 blocks][256 q] f32
#define WS_END8     35063808u
#define WS_PACC4    WS_PACKED   // small-ws overlays
#define WS_PML4     WS_MASKQ

// ---------------------------------------------------------------------------
// prep+pack fused. grid (64, 8, 5): z<4 -> pack mask batch z; z==4 -> prep.
// ---------------------------------------------------------------------------
__global__ __launch_bounds__(256) void prep_pack_kernel(
    const float* __restrict__ mask,
    const float* __restrict__ mqw1, const float* __restrict__ mkw1,
    const float* __restrict__ mqw2, const float* __restrict__ mkw2,
    const float* __restrict__ caw1, const float* __restrict__ caw2,
    _Float16* __restrict__ packed,
    _Float16* __restrict__ ApackConv, _Float16* __restrict__ ApackW2s,
    _Float16* __restrict__ ApackCA, _Float16* __restrict__ ApackW2K4)
{
    int tid = threadIdx.x;
    if (blockIdx.z < 4) {
        int ich = blockIdx.y, b = blockIdx.z;
        _Float16* Pb = packed + ((size_t)b * 8 + ich) * 130 * 130 * 8;
        if (blockIdx.x < 2) {
            for (int p = blockIdx.x * 260 + tid; p < (int)(blockIdx.x + 1) * 260; p += 256) {
                int row, col;
                if (p < 130)      { row = 0;       col = p; }
                else if (p < 260) { row = 129;     col = p - 130; }
                else if (p < 390) { row = p - 260; col = 0; }
                else              { row = p - 390; col = 129; }
                half8 z = {};
                *(half8*)(Pb + ((size_t)row * 130 + col) * 8) = z;
            }
        }
        int x = tid & 127;
        int sy = blockIdx.x * 2 + (tid >> 7);
        half8 v;
#pragma unroll
        for (int cc = 0; cc < 8; cc++)
            v[cc] = (_Float16)mask[(((size_t)(b * 64 + ich * 8 + cc)) * 128 + sy) * 128 + x];
        *(half8*)(Pb + (((size_t)(sy + 1)) * 130 + (x + 1)) * 8) = v;
        return;
    }
    int tid0 = (blockIdx.y * 64 + blockIdx.x) * 256 + tid;
    const int stride = 512 * 256;
    for (int idx = tid0; idx < 73728; idx += stride) {
        int j = idx & 7, lane = (idx >> 3) & 63, mf = (idx >> 9) & 3;
        int ks18 = idx >> 11;
        int br = ks18 / 18, kstep = ks18 % 18;
        int oc = mf * 16 + (lane & 15);
        int g = lane >> 4;
        int k = kstep * 32 + g * 8 + j;
        int tap = k >> 6, ic = k & 63;
        int dy = tap / 3, dx = tap - dy * 3;
        const float* w1 = br ? mkw1 : mqw1;
        ApackConv[idx] = (_Float16)w1[((oc * 64 + ic) * 3 + dy) * 3 + dx];
    }
    for (int idx = tid0; idx < 2048; idx += stride) {
        int j = idx & 7, lane = (idx >> 3) & 63;
        int f = (idx >> 9) & 1, br = idx >> 10;
        int dc = lane & 15, g = lane >> 4;
        int kap = 16 * (2 * f + (j >> 2)) + 4 * g + (j & 3);
        const float* w2 = br ? mkw2 : mqw2;
        ApackW2s[idx] = (_Float16)((dc < 8) ? w2[dc * 64 + kap] : 0.f);
    }
    for (int idx = tid0; idx < 4096; idx += stride) {
        int j = idx & 7, lane = (idx >> 3) & 63, mf = (idx >> 9) & 3, f = idx >> 11;
        int cp = mf * 16 + (lane & 15), g = lane >> 4;
        int kap = 16 * (2 * f + (j >> 2)) + 4 * g + (j & 3);
        ApackCA[idx] = (_Float16)caw1[cp * 64 + kap];
    }
    for (int idx = tid0; idx < 4096; idx += stride) {
        int j = idx & 7, lane = (idx >> 3) & 63, mf = (idx >> 9) & 3, f = idx >> 11;
        int cc = mf * 16 + (lane & 15), g = lane >> 4;
        int cpk = f * 32 + g * 8 + j;
        ApackW2K4[idx] = (_Float16)caw2[cc * 64 + cpk];
    }
}

// ---------------------------------------------------------------------------
// K1: grid (2,64,6). z<4: conv3x3(mask)+relu+1x1 -> f16 masks (b=z).
//     z>=4: V-proj blocks (vb=(z-4)*128+by*2+bx): V = Wv*avgpool(x)+bv,
//     tile-slot permuted f16. Shared LDS union (36KB).
// ---------------------------------------------------------------------------
__global__ __launch_bounds__(256) void conv_vproj_kernel(
    const _Float16* __restrict__ packed,
    const _Float16* __restrict__ ApackConv,
    const _Float16* __restrict__ ApackW2s,
    const float* __restrict__ mqb1, const float* __restrict__ mqb2,
    const float* __restrict__ mkb1, const float* __restrict__ mkb2,
    const float* __restrict__ xg,
    const float* __restrict__ Wv, const float* __restrict__ bv,
    _Float16* __restrict__ maskq, _Float16* __restrict__ maskk,
    _Float16* __restrict__ Vg)
{
    __shared__ __align__(16) char shmem[36864];
    int tid = threadIdx.x;

    if (blockIdx.z >= 4) {
        // ---- V-proj ----
        float* xw  = (float*)shmem;            // [64 ic][32 j] pooled
        float* lWv = (float*)(shmem + 16384);  // 4096 f32 — wait: 64x32=2048 f32=8KB
        // layout: xw 8KB at 0; lWv 16KB at 8192
        lWv = (float*)(shmem + 8192);
        int vb = (blockIdx.z - 4) * 128 + blockIdx.y * 2 + blockIdx.x;
        int b = vb >> 6, i = vb & 63;
        for (int idx = tid; idx < 2048; idx += 256) {
            int ic = idx >> 5, j = idx & 31;
            const float* px = xg + ((size_t)(b * 64 + ic) * 128 + 2 * i) * 128 + 2 * j;
            xw[idx] = 0.25f * (px[0] + px[1] + px[128] + px[129]);
        }
        for (int idx = tid; idx < 4096; idx += 256) lWv[idx] = Wv[idx];
        __syncthreads();
        // 256 thr: c0 = tid>>5 (8 c-base), jp = tid&31 -> j = jp (32 j's of this half?)
        // Each (b,i) has 64 pooled cols; vb covers all 64? xw only 32 j!
        // Fix: two j-halves per block: loop jh in {0,1}, restage.
        for (int jh = 0; jh < 2; jh++) {
            if (jh == 1) {
                __syncthreads();
                for (int idx = tid; idx < 2048; idx += 256) {
                    int ic = idx >> 5, j = idx & 31;
                    const float* px = xg + ((size_t)(b * 64 + ic) * 128 + 2 * i) * 128 + 2 * (32 + j);
                    xw[idx] = 0.25f * (px[0] + px[1] + px[128] + px[129]);
                }
                __syncthreads();
            }
            int c0 = tid >> 5;
            int jl = tid & 31;
            float acc0[8];
#pragma unroll
            for (int u = 0; u < 8; u++) acc0[u] = bv[c0 + 8 * u];
            for (int ic = 0; ic < 64; ic++) {
                float xv = xw[ic * 32 + jl];
#pragma unroll
                for (int u = 0; u < 8; u++)
                    acc0[u] += lWv[(c0 + 8 * u) * 64 + ic] * xv;
            }
            int j0 = jh * 32 + jl;
            int f = j0 >> 5, gg = (j0 & 15) >> 2, hi = (j0 >> 4) & 1;
            int off = (f * 4 + gg) * 8 + (j0 & 3) + 4 * hi;
#pragma unroll
            for (int u = 0; u < 8; u++) {
                int c = c0 + 8 * u;
                Vg[(size_t)(b * 64 + c) * 4096 + i * 64 + off] = (_Float16)acc0[u];
            }
        }
        return;
    }

    // ---- conv ----
    _Float16* S = (_Float16*)shmem; // [ich8][prow4][col72][8] = 36864 B
    int lane = tid & 63, w = tid >> 6;
    int x0 = blockIdx.x * 64;
    int y0 = blockIdx.y * 2;
    int b = blockIdx.z;
    int row = w & 1, br = w >> 1;
    int q = lane & 15, g = lane >> 4;

    const _Float16* Pb = packed + (size_t)b * 8 * 130 * 130 * 8;
#pragma unroll
    for (int i = 0; i < 8; i++) {
        int p = w * 8 + i;
        int ich = p >> 2, pr = p & 3;
        const _Float16* src = Pb + (((size_t)ich * 130 + (y0 + pr)) * 130 + x0) * 8;
        _Float16* dst = S + ((ich * 4 + pr) * 72) * 8;
        gload16(src + lane * 8, dst);
        if (lane < 8) gload16(src + (64 + lane) * 8, dst + 64 * 8);
    }
    __syncthreads();

    const _Float16* Ab = ApackConv + br * 36864;
    f32x4 acc[4][4] = {};
    for (int kstep = 0; kstep < 18; kstep++) {
        int tap = kstep >> 1;
        int dyv = tap / 3, dxv = tap - dyv * 3;
        int ich = (kstep & 1) * 4 + g;
        const _Float16* srow = S + ((ich * 4 + row + dyv) * 72 + q + dxv) * 8;
        half8 bf[4];
#pragma unroll
        for (int nf = 0; nf < 4; nf++)
            bf[nf] = *(const half8*)(srow + nf * 128);
        const _Float16* Ak = Ab + kstep * 2048 + lane * 8;
#pragma unroll
        for (int mf = 0; mf < 4; mf++) {
            half8 af = *(const half8*)(Ak + mf * 512);
#pragma unroll
            for (int nf = 0; nf < 4; nf++)
                acc[mf][nf] = mfma16(af, bf[nf], acc[mf][nf]);
        }
    }
    const float* b1p = br ? mkb1 : mqb1;
    const float* b2p = br ? mkb2 : mqb2;
    _Float16* outp = br ? maskk : maskq;
    float b1v[16];
#pragma unroll
    for (int mf = 0; mf < 4; mf++)
#pragma unroll
        for (int r = 0; r < 4; r++) b1v[mf * 4 + r] = b1p[mf * 16 + g * 4 + r];
    f32x4 acc2[4] = {};
#pragma unroll
    for (int f = 0; f < 2; f++) {
        half8 a2 = *(const half8*)(ApackW2s + (br * 2 + f) * 512 + lane * 8);
#pragma unroll
        for (int nf = 0; nf < 4; nf++) {
            half8 b2f;
#pragma unroll
            for (int j = 0; j < 8; j++) {
                int mfj = 2 * f + (j >> 2), rj = j & 3;
                b2f[j] = (_Float16)fmaxf(acc[mfj][nf][rj] + b1v[mfj * 4 + rj], 0.f);
            }
            acc2[nf] = mfma16(a2, b2f, acc2[nf]);
        }
    }
    if (g < 2) {
        int y = y0 + row;
#pragma unroll
        for (int r = 0; r < 4; r++) {
            int dc = g * 4 + r;
            float bb = b2p[dc];
#pragma unroll
            for (int nf = 0; nf < 4; nf++)
                outp[((size_t)(b * 8 + dc) * 128 + y) * 128 + (x0 + nf * 16 + q)] =
                    (_Float16)(acc2[nf][r] + bb);
        }
    }
}

// ---------------------------------------------------------------------------
// K2: QK-proj only. 256 thr per (b,i); xr staged f16 (32KB).
// ---------------------------------------------------------------------------
__global__ __launch_bounds__(256) void qkproj_kernel(
    const float* __restrict__ xg,
    const _Float16* __restrict__ maskq, const _Float16* __restrict__ maskk,
    const float* __restrict__ Wq, const float* __restrict__ bq,
    const float* __restrict__ Wk, const float* __restrict__ bk,
    const float* __restrict__ a1p, const float* __restrict__ a2p,
    _Float16* __restrict__ Qg, _Float16* __restrict__ Kg)
{
    __shared__ _Float16 xr[16384]; // [ic][ysel][x]
    __shared__ float lWq[512], lWk[512];
    int tid = threadIdx.x;
    int b = blockIdx.x >> 6, i = blockIdx.x & 63;

    for (int idx = tid; idx < 16384; idx += 256) {
        int ic = idx >> 8, rem = idx & 255;
        xr[idx] = (_Float16)xg[((size_t)(b * 64 + ic) * 128 + (2 * i + (rem >> 7))) * 128 + (rem & 127)];
    }
    lWq[tid] = Wq[tid]; lWq[tid] = Wq[tid];
    lWq[tid + 256] = Wq[tid + 256];
    lWk[tid] = Wk[tid];
    lWk[tid + 256] = Wk[tid + 256];
    __syncthreads();

    int branch = tid >> 7;
    int t = tid & 127;
    int ysel = t & 1;
    int j = (t >> 1) & 63;
    const float* W = branch ? lWk : lWq;
    const float* bias = branch ? bk : bq;
    float alpha = branch ? a2p[0] : a1p[0];
    const _Float16* mq = branch ? maskk : maskq;
    _Float16* outg = branch ? Kg : Qg;
    int x0c = 2 * j, x1c = 2 * j + 1;
    float aq0[8], aq1[8];
#pragma unroll
    for (int dc = 0; dc < 8; dc++) { float bb = bias[dc]; aq0[dc] = bb; aq1[dc] = bb; }
    for (int ic = 0; ic < 64; ic++) {
        float xv0 = (float)xr[ic * 256 + ysel * 128 + x0c];
        float xv1 = (float)xr[ic * 256 + ysel * 128 + x1c];
#pragma unroll
        for (int dc = 0; dc < 8; dc++) {
            float ww = W[dc * 64 + ic];
            aq0[dc] += ww * xv0; aq1[dc] += ww * xv1;
        }
    }
    int yy = 2 * i + ysel;
    half8 vq;
#pragma unroll
    for (int dc = 0; dc < 8; dc++) {
        size_t mbase = ((size_t)(b * 8 + dc) * 128 + yy) * 128;
        float m0v = (float)mq[mbase + x0c], m1v = (float)mq[mbase + x1c];
        float s = aq0[dc] * (alpha * m0v + (1.f - alpha))
                + aq1[dc] * (alpha * m1v + (1.f - alpha));
        s += __shfl_xor(s, 1);
        vq[dc] = (_Float16)(0.25f * s);
    }
    if (ysel == 0)
        *(half8*)(outg + ((size_t)b * 4096 + i * 64 + j) * 8) = vq;
}

// ---------------------------------------------------------------------------
// K3: flash attention, SPLIT=8, no max-tracking, 32 q/wave (dual-q, R8 cfg).
// V (64KB) + K (8KB) staged to LDS once; 8 key-tiles barrier-free.
// Denominator via MFMA-ones. Epilogue fuses z = ca_w1 * acc.
// Block = 8 waves x 32 q = 256 q. bid: qt=bid&15, b=(bid>>4)&bmask, s=bid>>sshift.
// ---------------------------------------------------------------------------
__global__ __launch_bounds__(512, 4) void attn_kernel(
    const _Float16* __restrict__ Qg, const _Float16* __restrict__ Kg,
    const _Float16* __restrict__ Vg, const _Float16* __restrict__ ApackCA,
    _Float16* __restrict__ pacc, float* __restrict__ pml,
    int bmask, int sshift, int bbase)
{
    __shared__ __align__(16) _Float16 Vlds[8 * 4096];
    __shared__ __align__(16) _Float16 Klds[8 * 512];
    int tid = threadIdx.x, lane = tid & 63, w = tid >> 6;
    int q = lane & 15, g = lane >> 4;
    int bid = blockIdx.x;
    int qt = bid & 15, b = bbase + ((bid >> 4) & bmask), s = bid >> sshift;

    const _Float16* Kb = Kg + ((size_t)b * 4096 + s * 512) * 8;
    const _Float16* Vbase = Vg + (size_t)b * 64 * 4096 + s * 512;

    {
        int cc = w * 8 + (lane >> 3);
        int chl = (lane & 7) ^ (cc & 7);
        const _Float16* src0 = Vbase + (size_t)cc * 4096 + chl * 8;
#pragma unroll
        for (int t = 0; t < 8; t++)
            gload16(src0 + t * 64, Vlds + t * 4096 + w * 512);
        gload16(Kb + (size_t)(w * 64 + lane) * 8, Klds + w * 512);
    }
    half8 qf0 = {}, qf1 = {};
    if (g == 0) {
        int qb = qt * 256 + w * 32 + q;
        half8 r0 = *(const half8*)(Qg + ((size_t)b * 4096 + qb) * 8);
        half8 r1 = *(const half8*)(Qg + ((size_t)b * 4096 + qb + 16) * 8);
#pragma unroll
        for (int j = 0; j < 8; j++) {
            qf0[j] = (_Float16)((float)r0[j] * 1.44269504f);
            qf1[j] = (_Float16)((float)r1[j] * 1.44269504f);
        }
    }
    __syncthreads();

    half8 ones;
#pragma unroll
    for (int j = 0; j < 8; j++) ones[j] = (_Float16)1.f;

    f32x4 acc0[4] = {}, acc1[4] = {};
    f32x4 accl0 = {}, accl1 = {};
    const f32x4 zero4 = {};

#pragma unroll 2
    for (int t = 0; t < 8; t++) {
        const _Float16* Kt = Klds + t * 512;
        half8 af0 = *(const half8*)(Kt + q * 8);
        half8 af1 = *(const half8*)(Kt + (16 + q) * 8);
        half8 af2 = *(const half8*)(Kt + (32 + q) * 8);
        half8 af3 = *(const half8*)(Kt + (48 + q) * 8);

        half8 pb00, pb01, pb10, pb11;
        {
            f32x4 s0 = mfma16(af0, qf0, zero4);
            f32x4 s1 = mfma16(af1, qf0, zero4);
            f32x4 s2 = mfma16(af2, qf0, zero4);
            f32x4 s3 = mfma16(af3, qf0, zero4);
            f32x4 e0, e1, e2, e3;
#pragma unroll
            for (int r = 0; r < 4; r++) {
                e0[r] = __builtin_amdgcn_exp2f(s0[r]);
                e1[r] = __builtin_amdgcn_exp2f(s1[r]);
                e2[r] = __builtin_amdgcn_exp2f(s2[r]);
                e3[r] = __builtin_amdgcn_exp2f(s3[r]);
            }
            pb00 = pk8(e0, e1); pb01 = pk8(e2, e3);
            accl0 = mfma16(ones, pb00, accl0);
            accl0 = mfma16(ones, pb01, accl0);
        }
        {
            f32x4 s0 = mfma16(af0, qf1, zero4);
            f32x4 s1 = mfma16(af1, qf1, zero4);
            f32x4 s2 = mfma16(af2, qf1, zero4);
            f32x4 s3 = mfma16(af3, qf1, zero4);
            f32x4 e0, e1, e2, e3;
#pragma unroll
            for (int r = 0; r < 4; r++) {
                e0[r] = __builtin_amdgcn_exp2f(s0[r]);
                e1[r] = __builtin_amdgcn_exp2f(s1[r]);
                e2[r] = __builtin_amdgcn_exp2f(s2[r]);
                e3[r] = __builtin_amdgcn_exp2f(s3[r]);
            }
            pb10 = pk8(e0, e1); pb11 = pk8(e2, e3);
            accl1 = mfma16(ones, pb10, accl1);
            accl1 = mfma16(ones, pb11, accl1);
        }
        const _Float16* Vl = Vlds + t * 4096;
        int sw = q & 7;
        __builtin_amdgcn_s_setprio(1);
#pragma unroll
        for (int mfc = 0; mfc < 4; mfc++) {
            const _Float16* vr = Vl + (mfc * 16 + q) * 64;
            half8 av0 = *(const half8*)(vr + (g ^ sw) * 8);
            half8 av1 = *(const half8*)(vr + ((4 + g) ^ sw) * 8);
            acc0[mfc] = mfma16(av0, pb00, acc0[mfc]);
            acc1[mfc] = mfma16(av0, pb10, acc1[mfc]);
            acc0[mfc] = mfma16(av1, pb01, acc0[mfc]);
            acc1[mfc] = mfma16(av1, pb11, acc1[mfc]);
        }
        __builtin_amdgcn_s_setprio(0);
    }

    half8 a3[8];
#pragma unroll
    for (int i = 0; i < 8; i++) a3[i] = *(const half8*)(ApackCA + i * 512 + lane * 8);
    {
        half8 ob0 = pk8(acc0[0], acc0[1]);
        half8 ob1 = pk8(acc0[2], acc0[3]);
        f32x4 z[4] = {};
#pragma unroll
        for (int mf2 = 0; mf2 < 4; mf2++) {
            z[mf2] = mfma16(a3[mf2], ob0, z[mf2]);
            z[mf2] = mfma16(a3[4 + mf2], ob1, z[mf2]);
        }
        size_t prow = ((size_t)bid * 256 + w * 32 + q) * 64;
#pragma unroll
        for (int mf2 = 0; mf2 < 4; mf2++)
            *(half4v*)(pacc + prow + mf2 * 16 + g * 4) = pk4(z[mf2]);
        if (g == 0) pml[bid * 256 + w * 32 + q] = accl0[0];
    }
    {
        half8 ob0 = pk8(acc1[0], acc1[1]);
        half8 ob1 = pk8(acc1[2], acc1[3]);
        f32x4 z[4] = {};
#pragma unroll
        for (int mf2 = 0; mf2 < 4; mf2++) {
            z[mf2] = mfma16(a3[mf2], ob0, z[mf2]);
            z[mf2] = mfma16(a3[4 + mf2], ob1, z[mf2]);
        }
        size_t prow = ((size_t)bid * 256 + w * 32 + 16 + q) * 64;
#pragma unroll
        for (int mf2 = 0; mf2 < 4; mf2++)
            *(half4v*)(pacc + prow + mf2 * 16 + g * 4) = pk4(z[mf2]);
        if (g == 0) pml[bid * 256 + w * 32 + 16 + q] = accl1[0];
    }
}

// ---------------------------------------------------------------------------
// K3b: elementwise combine (small-ws path only). tiles are 256-q.
// ---------------------------------------------------------------------------
__global__ __launch_bounds__(256) void combine_kernel(
    const _Float16* __restrict__ pacc, const float* __restrict__ pml,
    const float* __restrict__ cb1, _Float16* __restrict__ zb,
    int tps, int bbase)
{
    int T = blockIdx.x * 256 + threadIdx.x;
    int e = T & 7, row = T >> 3;
    int brel = row >> 12, qg = row & 4095;
    int qt16 = qg >> 8, ql = qg & 255;
    int tb0 = brel * 16 + qt16;

    float sum[8] = {};
    float L = 0.f;
    for (int s = 0; s < 8; s++) {
        int tile = s * tps + tb0;
        half8 v = *(const half8*)(pacc + ((size_t)tile * 256 + ql) * 64 + e * 8);
#pragma unroll
        for (int i = 0; i < 8; i++) sum[i] += (float)v[i];
        L += pml[tile * 256 + ql];
    }
    float inv = 1.f / L;
    half8 o;
#pragma unroll
    for (int i = 0; i < 8; i++) o[i] = (_Float16)(sum[i] * inv + cb1[e * 8 + i]);
    *(half8*)(zb + ((size_t)(bbase + brel) * 4096 + qg) * 64 + e * 8) = o;
}

// ---------------------------------------------------------------------------
// K4: out = ca_w2 * relu(upsample2x(z)) + ca_b2 + x. 512-thread blocks,
// 8 rows x 32 px; grid (4,16,4). FUSED=1: combine folded into staging.
// ---------------------------------------------------------------------------
template <int FUSED>
__global__ __launch_bounds__(512) void post_kernel(
    const _Float16* __restrict__ zg,
    const _Float16* __restrict__ pacc, const float* __restrict__ pml,
    const float* __restrict__ cb1,
    const float* __restrict__ xg,
    const _Float16* __restrict__ ApackW2K4, const float* __restrict__ cb2,
    float* __restrict__ outg)
{
    __shared__ _Float16 zt[6 * 18 * 72];
    int tid = threadIdx.x, lane = tid & 63, w = tid >> 6;
    int x0 = blockIdx.x * 32, y0 = blockIdx.y * 8, b = blockIdx.z;
    int r0 = 4 * (int)blockIdx.y - 1;
    int cbs = 16 * (int)blockIdx.x - 1;
    const _Float16* zgb = zg + (size_t)b * 4096 * 64;
    for (int idx = tid; idx < 864; idx += 512) {
        int rowi = idx >> 3, ch = idx & 7;
        int r = rowi / 18, col = rowi - r * 18;
        int zr = min(max(r0 + r, 0), 63);
        int zc = min(max(cbs + col, 0), 63);
        if constexpr (FUSED) {
            int zq = zr * 64 + zc;
            int tb = b * 16 + (zq >> 8);
            int ql = zq & 255;
            float sum[8] = {};
            float L = 0.f;
#pragma unroll
            for (int s = 0; s < 8; s++) {
                int tile = s * 64 + tb;
                half8 v = *(const half8*)(pacc + ((size_t)tile * 256 + ql) * 64 + ch * 8);
#pragma unroll
                for (int i2 = 0; i2 < 8; i2++) sum[i2] += (float)v[i2];
                L += pml[tile * 256 + ql];
            }
            float inv = 1.f / L;
            half8 o;
#pragma unroll
            for (int i2 = 0; i2 < 8; i2++) o[i2] = (_Float16)(sum[i2] * inv + cb1[ch * 8 + i2]);
            *(half8*)&zt[(r * 18 + col) * 72 + ch * 8] = o;
        } else {
            half8 v = *(const half8*)(zgb + ((size_t)(zr * 64 + zc)) * 64 + ch * 8);
            *(half8*)&zt[(r * 18 + col) * 72 + ch * 8] = v;
        }
    }
    __syncthreads();

    int q = lane & 15, g = lane >> 4;
    int y = y0 + w;
    int ra = (w >> 1) + (w & 1);
    float wyA = (w & 1) ? 0.75f : 0.25f;
    float wyB = 1.f - wyA;
    f32x4 acc[4][2] = {};
#pragma unroll
    for (int f = 0; f < 2; f++) {
        half8 a[4];
#pragma unroll
        for (int mf = 0; mf < 4; mf++)
            a[mf] = *(const half8*)(ApackW2K4 + (f * 4 + mf) * 512 + lane * 8);
#pragma unroll
        for (int nf = 0; nf < 2; nf++) {
            int pxl = nf * 16 + q;
            int ca = (pxl >> 1) + (pxl & 1);
            float wxA = (pxl & 1) ? 0.75f : 0.25f;
            float wxB = 1.f - wxA;
            half8 bfrag;
#pragma unroll
            for (int qd = 0; qd < 2; qd++) {
                int cpb = f * 32 + g * 8 + qd * 4;
                const _Float16* z00 = &zt[(ra * 18 + ca) * 72 + cpb];
                half4v h00 = *(const half4v*)z00;
                half4v h01 = *(const half4v*)(z00 + 72);
                half4v h10 = *(const half4v*)(z00 + 18 * 72);
                half4v h11 = *(const half4v*)(z00 + 18 * 72 + 72);
#pragma unroll
                for (int e = 0; e < 4; e++) {
                    float zu = ((float)h00[e] * wxA + (float)h01[e] * wxB) * wyA
                             + ((float)h10[e] * wxA + (float)h11[e] * wxB) * wyB;
                    bfrag[qd * 4 + e] = (_Float16)fmaxf(zu, 0.f);
                }
            }
#pragma unroll
            for (int mf = 0; mf < 4; mf++) acc[mf][nf] = mfma16(a[mf], bfrag, acc[mf][nf]);
        }
    }
#pragma unroll
    for (int mf = 0; mf < 4; mf++)
#pragma unroll
        for (int r = 0; r < 4; r++) {
            int c = mf * 16 + g * 4 + r;
            float bb = cb2[c];
#pragma unroll
            for (int nf = 0; nf < 2; nf++) {
                size_t oidx = ((size_t)(b * 64 + c) * 128 + y) * 128 + x0 + nf * 16 + q;
                outg[oidx] = acc[mf][nf][r] + bb + xg[oidx];
            }
        }
}

// ---------------------------------------------------------------------------
extern "C" void kernel_launch(void* const* d_in, const int* in_sizes, int n_in,
                              void* d_out, int out_size, void* d_ws, size_t ws_size,
                              hipStream_t stream)
{
    const float* x    = (const float*)d_in[0];
    const float* mask = (const float*)d_in[1];
    const float* Wq   = (const float*)d_in[2];
    const float* bq   = (const float*)d_in[3];
    const float* Wk   = (const float*)d_in[4];
    const float* bk   = (const float*)d_in[5];
    const float* Wv   = (const float*)d_in[6];
    const float* bv   = (const float*)d_in[7];
    const float* a1   = (const float*)d_in[8];
    const float* a2   = (const float*)d_in[9];
    const float* mqw1 = (const float*)d_in[10];
    const float* mqb1 = (const float*)d_in[11];
    const float* mqw2 = (const float*)d_in[12];
    const float* mqb2 = (const float*)d_in[13];
    const float* mkw1 = (const float*)d_in[14];
    const float* mkb1 = (const float*)d_in[15];
    const float* mkw2 = (const float*)d_in[16];
    const float* mkb2 = (const float*)d_in[17];
    const float* caw1 = (const float*)d_in[18];
    const float* cab1 = (const float*)d_in[19];
    const float* caw2 = (const float*)d_in[20];
    const float* cab2 = (const float*)d_in[21];

    char* ws = (char*)d_ws;
    _Float16* ApackConv = (_Float16*)(ws + WS_APCONV);
    _Float16* ApackW2s  = (_Float16*)(ws + WS_APW2S);
    _Float16* ApackCA   = (_Float16*)(ws + WS_APCA);
    _Float16* ApackW2K4 = (_Float16*)(ws + WS_APW2K4);
    _Float16* packed    = (_Float16*)(ws + WS_PACKED);
    _Float16* maskq     = (_Float16*)(ws + WS_MASKQ);
    _Float16* maskk     = (_Float16*)(ws + WS_MASKK);
    _Float16* Qg16      = (_Float16*)(ws + WS_Q16);
    _Float16* Kg16      = (_Float16*)(ws + WS_K16);
    _Float16* Vb        = (_Float16*)(ws + WS_V16);
    _Float16* zb        = (_Float16*)(ws + WS_ZB);

    prep_pack_kernel<<<dim3(64, 8, 5), dim3(256), 0, stream>>>(
        mask, mqw1, mkw1, mqw2, mkw2, caw1, caw2,
        packed, ApackConv, ApackW2s, ApackCA, ApackW2K4);
    conv_vproj_kernel<<<dim3(2, 64, 6), dim3(256), 0, stream>>>(
        packed, ApackConv, ApackW2s, mqb1, mqb2, mkb1, mkb2,
        x, Wv, bv, maskq, maskk, Vb);
    qkproj_kernel<<<dim3(256), dim3(256), 0, stream>>>(
        x, maskq, maskk, Wq, bq, Wk, bk, a1, a2, Qg16, Kg16);

    bool big = (ws_size >= (size_t)WS_END8);
    if (big) {
        _Float16* pacc = (_Float16*)(ws + WS_PACC8);
        float*    pml  = (float*)(ws + WS_PML8);
        attn_kernel<<<dim3(512), dim3(512), 0, stream>>>(
            Qg16, Kg16, Vb, ApackCA, pacc, pml, 3, 6, 0);
        post_kernel<1><<<dim3(4, 16, 4), dim3(512), 0, stream>>>(
            zb, pacc, pml, cab1, x, ApackW2K4, cab2, (float*)d_out);
    } else {
        _Float16* pacc = (_Float16*)(ws + WS_PACC4);
        float*    pml  = (float*)(ws + WS_PML4);
        for (int bbase = 0; bbase < 4; bbase += 2) {
            attn_kernel<<<dim3(256), dim3(512), 0, stream>>>(
                Qg16, Kg16, Vb, ApackCA, pacc, pml, 1, 5, bbase);
            combine_kernel<<<dim3(256), dim3(256), 0, stream>>>(pacc, pml, cab1, zb, 32, bbase);
        }
        post_kernel<0><<<dim3(4, 16, 4), dim3(512), 0, stream>>>(
            zb, nullptr, nullptr, cab1, x, ApackW2K4, cab2, (float*)d_out);
    }
}

// Round 11
// 65.349 us; speedup vs baseline: 1.3453x; 1.3453x over previous
//
#include <hip/hip_runtime.h>
#include <hip/hip_bf16.h>

typedef _Float16 half8 __attribute__((ext_vector_type(8)));
typedef _Float16 half4v __attribute__((ext_vector_type(4)));
typedef _Float16 half2v __attribute__((ext_vector_type(2)));
typedef __fp16 pkh2 __attribute__((ext_vector_type(2)));
typedef float f32x4 __attribute__((ext_vector_type(4)));

static __device__ __forceinline__ f32x4 mfma16(half8 a, half8 b, f32x4 c) {
    return __builtin_amdgcn_mfma_f32_16x16x32_f16(a, b, c, 0, 0, 0);
}

typedef const __attribute__((address_space(1))) unsigned int* gas_ptr;
typedef __attribute__((address_space(3))) unsigned int* las_ptr;
static __device__ __forceinline__ void gload16(const void* g, void* l) {
    __builtin_amdgcn_global_load_lds((gas_ptr)g, (las_ptr)l, 16, 0, 0);
}

static __device__ __forceinline__ half2v cvt2(float a, float b) {
    pkh2 t = __builtin_amdgcn_cvt_pkrtz(a, b);
    return __builtin_bit_cast(half2v, t);
}
static __device__ __forceinline__ half8 pk8(f32x4 a, f32x4 b) {
    half2v x0 = cvt2(a[0], a[1]);
    half2v x1 = cvt2(a[2], a[3]);
    half2v x2 = cvt2(b[0], b[1]);
    half2v x3 = cvt2(b[2], b[3]);
    half4v lo = __builtin_shufflevector(x0, x1, 0, 1, 2, 3);
    half4v hi = __builtin_shufflevector(x2, x3, 0, 1, 2, 3);
    return __builtin_shufflevector(lo, hi, 0, 1, 2, 3, 4, 5, 6, 7);
}
static __device__ __forceinline__ half4v pk4(f32x4 a) {
    half2v x0 = cvt2(a[0], a[1]);
    half2v x1 = cvt2(a[2], a[3]);
    return __builtin_shufflevector(x0, x1, 0, 1, 2, 3);
}

// ---------------- workspace layout (bytes) ----------------
#define WS_APCONV   0u          // 147456
#define WS_APW2S    147456u     // 4096
#define WS_APCA     151552u     // 8192
#define WS_APW2K4   159744u     // 8192
#define WS_PACKED   196608u     // 8,652,800   [b][8][130][130][8] f16
#define WS_MASKQ    8849408u    // 1,048,576   [b][8][128][128] f16
#define WS_MASKK    10946560u   // 1,048,576
#define WS_Q16      13043712u   // 262,144     [b][4096][8] f16
#define WS_K16      13305856u   // 262,144
#define WS_V16      13568000u   // 2,097,152   [b][64][4096] f16 (tile-slot permuted)
#define WS_ZB       15665152u   // 2,097,152   [b][4096][64] f16 (small path only)
#define WS_PACC8    17762304u   // 16,777,216  [512 blocks][256 q][64 c] f16
#define WS_PML8     34539520u   // 524,288     [512 blocks][256 q] f32
#define WS_END8     35063808u
#define WS_PACC4    WS_PACKED   // small-ws overlays
#define WS_PML4     WS_MASKQ

// ---------------------------------------------------------------------------
// prep+pack fused. grid (64, 8, 5): z<4 -> pack mask batch z; z==4 -> prep.
// ---------------------------------------------------------------------------
__global__ __launch_bounds__(256) void prep_pack_kernel(
    const float* __restrict__ mask,
    const float* __restrict__ mqw1, const float* __restrict__ mkw1,
    const float* __restrict__ mqw2, const float* __restrict__ mkw2,
    const float* __restrict__ caw1, const float* __restrict__ caw2,
    _Float16* __restrict__ packed,
    _Float16* __restrict__ ApackConv, _Float16* __restrict__ ApackW2s,
    _Float16* __restrict__ ApackCA, _Float16* __restrict__ ApackW2K4)
{
    int tid = threadIdx.x;
    if (blockIdx.z < 4) {
        int ich = blockIdx.y, b = blockIdx.z;
        _Float16* Pb = packed + ((size_t)b * 8 + ich) * 130 * 130 * 8;
        if (blockIdx.x < 2) {
            for (int p = blockIdx.x * 260 + tid; p < (int)(blockIdx.x + 1) * 260; p += 256) {
                int row, col;
                if (p < 130)      { row = 0;       col = p; }
                else if (p < 260) { row = 129;     col = p - 130; }
                else if (p < 390) { row = p - 260; col = 0; }
                else              { row = p - 390; col = 129; }
                half8 z = {};
                *(half8*)(Pb + ((size_t)row * 130 + col) * 8) = z;
            }
        }
        int x = tid & 127;
        int sy = blockIdx.x * 2 + (tid >> 7);
        half8 v;
#pragma unroll
        for (int cc = 0; cc < 8; cc++)
            v[cc] = (_Float16)mask[(((size_t)(b * 64 + ich * 8 + cc)) * 128 + sy) * 128 + x];
        *(half8*)(Pb + (((size_t)(sy + 1)) * 130 + (x + 1)) * 8) = v;
        return;
    }
    int tid0 = (blockIdx.y * 64 + blockIdx.x) * 256 + tid;
    const int stride = 512 * 256;
    for (int idx = tid0; idx < 73728; idx += stride) {
        int j = idx & 7, lane = (idx >> 3) & 63, mf = (idx >> 9) & 3;
        int ks18 = idx >> 11;
        int br = ks18 / 18, kstep = ks18 % 18;
        int oc = mf * 16 + (lane & 15);
        int g = lane >> 4;
        int k = kstep * 32 + g * 8 + j;
        int tap = k >> 6, ic = k & 63;
        int dy = tap / 3, dx = tap - dy * 3;
        const float* w1 = br ? mkw1 : mqw1;
        ApackConv[idx] = (_Float16)w1[((oc * 64 + ic) * 3 + dy) * 3 + dx];
    }
    for (int idx = tid0; idx < 2048; idx += stride) {
        int j = idx & 7, lane = (idx >> 3) & 63;
        int f = (idx >> 9) & 1, br = idx >> 10;
        int dc = lane & 15, g = lane >> 4;
        int kap = 16 * (2 * f + (j >> 2)) + 4 * g + (j & 3);
        const float* w2 = br ? mkw2 : mqw2;
        ApackW2s[idx] = (_Float16)((dc < 8) ? w2[dc * 64 + kap] : 0.f);
    }
    for (int idx = tid0; idx < 4096; idx += stride) {
        int j = idx & 7, lane = (idx >> 3) & 63, mf = (idx >> 9) & 3, f = idx >> 11;
        int cp = mf * 16 + (lane & 15), g = lane >> 4;
        int kap = 16 * (2 * f + (j >> 2)) + 4 * g + (j & 3);
        ApackCA[idx] = (_Float16)caw1[cp * 64 + kap];
    }
    for (int idx = tid0; idx < 4096; idx += stride) {
        int j = idx & 7, lane = (idx >> 3) & 63, mf = (idx >> 9) & 3, f = idx >> 11;
        int cc = mf * 16 + (lane & 15), g = lane >> 4;
        int cpk = f * 32 + g * 8 + j;
        ApackW2K4[idx] = (_Float16)caw2[cc * 64 + cpk];
    }
}

// ---------------------------------------------------------------------------
// K1: conv3x3(mask)+b1 -> relu -> 1x1(->8)+b2 -> f16. ALL-LDS inner loop:
// branch A-pack (73.7KB) + 6-row input strip (56KB, 73-col pad) staged once
// via global_load_lds; 18 unrolled ksteps of pure ds_read_b128 + MFMA.
// Block = 4 rows x 64 px x ONE branch (4 waves). grid (2,32,8=b*2+br).
// ---------------------------------------------------------------------------
__global__ __launch_bounds__(256) void conv_mask_kernel(
    const _Float16* __restrict__ packed,
    const _Float16* __restrict__ ApackConv,
    const _Float16* __restrict__ ApackW2s,
    const float* __restrict__ mqb1, const float* __restrict__ mqb2,
    const float* __restrict__ mkb1, const float* __restrict__ mkb2,
    _Float16* __restrict__ maskq, _Float16* __restrict__ maskk)
{
    __shared__ __align__(16) _Float16 A[36864];  // [kstep18][mf4][lane64][8]
    __shared__ __align__(16) _Float16 S[28032];  // [ich8][pr6][col73][8]
    int tid = threadIdx.x;
    int lane = tid & 63, w = tid >> 6;
    int x0 = blockIdx.x * 64;
    int y0 = blockIdx.y * 4;
    int bz = blockIdx.z;
    int b = bz >> 1, br = bz & 1;
    int q = lane & 15, g = lane >> 4;

    // stage A: this branch's 73728 B, 18 x 1KB chunks per wave
    const _Float16* Ag = ApackConv + br * 36864;
#pragma unroll
    for (int i = 0; i < 18; i++) {
        int off = w * 9216 + i * 512;
        gload16(Ag + off + lane * 8, A + off);
    }
    // stage strip: 48 (ich,pr) rows of 72 cols (1152 B), 12 per wave
    const _Float16* Pb = packed + (size_t)b * 8 * 130 * 130 * 8;
#pragma unroll
    for (int i = 0; i < 12; i++) {
        int rr = w * 12 + i;
        int ich = rr / 6, pr = rr - ich * 6;
        const _Float16* src = Pb + (((size_t)ich * 130 + (y0 + pr)) * 130 + x0) * 8;
        _Float16* dst = S + (ich * 6 + pr) * 584; // 73*8
        gload16(src + lane * 8, dst);
        if (lane < 8) gload16(src + (64 + lane) * 8, dst + 512);
    }
    __syncthreads();

    f32x4 acc[4][4] = {};
#pragma unroll
    for (int kstep = 0; kstep < 18; kstep++) {
        int tap = kstep >> 1;
        int dyv = tap / 3, dxv = tap - dyv * 3;
        int ich = (kstep & 1) * 4 + g;
        const _Float16* srow = S + ((ich * 6 + w + dyv) * 73 + q + dxv) * 8;
        half8 bf[4];
#pragma unroll
        for (int nf = 0; nf < 4; nf++)
            bf[nf] = *(const half8*)(srow + nf * 128);
        const _Float16* Ak = A + kstep * 2048 + lane * 8;
#pragma unroll
        for (int mf = 0; mf < 4; mf++) {
            half8 af = *(const half8*)(Ak + mf * 512);
#pragma unroll
            for (int nf = 0; nf < 4; nf++)
                acc[mf][nf] = mfma16(af, bf[nf], acc[mf][nf]);
        }
    }
    const float* b1p = br ? mkb1 : mqb1;
    const float* b2p = br ? mkb2 : mqb2;
    _Float16* outp = br ? maskk : maskq;
    float b1v[16];
#pragma unroll
    for (int mf = 0; mf < 4; mf++)
#pragma unroll
        for (int r = 0; r < 4; r++) b1v[mf * 4 + r] = b1p[mf * 16 + g * 4 + r];
    f32x4 acc2[4] = {};
#pragma unroll
    for (int f = 0; f < 2; f++) {
        half8 a2 = *(const half8*)(ApackW2s + (br * 2 + f) * 512 + lane * 8);
#pragma unroll
        for (int nf = 0; nf < 4; nf++) {
            half8 b2f;
#pragma unroll
            for (int j = 0; j < 8; j++) {
                int mfj = 2 * f + (j >> 2), rj = j & 3;
                b2f[j] = (_Float16)fmaxf(acc[mfj][nf][rj] + b1v[mfj * 4 + rj], 0.f);
            }
            acc2[nf] = mfma16(a2, b2f, acc2[nf]);
        }
    }
    if (g < 2) {
        int y = y0 + w;
#pragma unroll
        for (int r = 0; r < 4; r++) {
            int dc = g * 4 + r;
            float bb = b2p[dc];
#pragma unroll
            for (int nf = 0; nf < 4; nf++)
                outp[((size_t)(b * 8 + dc) * 128 + y) * 128 + (x0 + nf * 16 + q)] =
                    (_Float16)(acc2[nf][r] + bb);
        }
    }
}

// ---------------------------------------------------------------------------
// K2: merged proj, 512 threads: xr staged once; t<256 -> V part, else Q/K.
// ---------------------------------------------------------------------------
__global__ __launch_bounds__(512) void proj_kernel(
    const float* __restrict__ xg,
    const _Float16* __restrict__ maskq, const _Float16* __restrict__ maskk,
    const float* __restrict__ Wq, const float* __restrict__ bq,
    const float* __restrict__ Wk, const float* __restrict__ bk,
    const float* __restrict__ Wv, const float* __restrict__ bv,
    const float* __restrict__ a1p, const float* __restrict__ a2p,
    _Float16* __restrict__ Qg, _Float16* __restrict__ Kg, _Float16* __restrict__ Vg)
{
    __shared__ float xr[16384];
    __shared__ float xw[4096];
    __shared__ float lWv[4096], lWq[512], lWk[512];
    int tid = threadIdx.x;
    int b = blockIdx.x >> 6, i = blockIdx.x & 63;

    for (int idx = tid; idx < 16384; idx += 512) {
        int ic = idx >> 8, rem = idx & 255;
        xr[idx] = xg[((size_t)(b * 64 + ic) * 128 + (2 * i + (rem >> 7))) * 128 + (rem & 127)];
    }
    for (int idx = tid; idx < 4096; idx += 512) lWv[idx] = Wv[idx];
    lWq[tid] = Wq[tid];
    lWk[tid] = Wk[tid];
    __syncthreads();
    for (int idx = tid; idx < 4096; idx += 512) {
        int ic = idx >> 6, j = idx & 63;
        const float* base = &xr[ic * 256 + 2 * j];
        xw[idx] = 0.25f * (base[0] + base[1] + base[128] + base[129]);
    }
    __syncthreads();

    if (tid < 256) {
        int c0 = tid >> 5;
        int j0 = (tid & 31) * 2;
        float acc0[8], acc1[8];
#pragma unroll
        for (int u = 0; u < 8; u++) { float bb = bv[c0 + 8 * u]; acc0[u] = bb; acc1[u] = bb; }
        for (int ic = 0; ic < 64; ic++) {
            float x0v = xw[ic * 64 + j0], x1v = xw[ic * 64 + j0 + 1];
#pragma unroll
            for (int u = 0; u < 8; u++) {
                float ww = lWv[(c0 + 8 * u) * 64 + ic];
                acc0[u] += ww * x0v; acc1[u] += ww * x1v;
            }
        }
        int f = j0 >> 5, gg = (j0 & 15) >> 2, hi = (j0 >> 4) & 1;
        int off = (f * 4 + gg) * 8 + (j0 & 3) + 4 * hi;
#pragma unroll
        for (int u = 0; u < 8; u++) {
            int c = c0 + 8 * u;
            _Float16* p = Vg + (size_t)(b * 64 + c) * 4096 + i * 64 + off;
            p[0] = (_Float16)acc0[u]; p[1] = (_Float16)acc1[u];
        }
    } else {
        int t = tid - 256;
        int branch = t >> 7;
        int ysel = t & 1;
        int j = (t >> 1) & 63;
        const float* W = branch ? lWk : lWq;
        const float* bias = branch ? bk : bq;
        float alpha = branch ? a2p[0] : a1p[0];
        const _Float16* mq = branch ? maskk : maskq;
        _Float16* outg = branch ? Kg : Qg;
        int x0c = 2 * j, x1c = 2 * j + 1;
        float aq0[8], aq1[8];
#pragma unroll
        for (int dc = 0; dc < 8; dc++) { float bb = bias[dc]; aq0[dc] = bb; aq1[dc] = bb; }
        for (int ic = 0; ic < 64; ic++) {
            float xv0 = xr[ic * 256 + ysel * 128 + x0c];
            float xv1 = xr[ic * 256 + ysel * 128 + x1c];
#pragma unroll
            for (int dc = 0; dc < 8; dc++) {
                float ww = W[dc * 64 + ic];
                aq0[dc] += ww * xv0; aq1[dc] += ww * xv1;
            }
        }
        int yy = 2 * i + ysel;
        half8 vq;
#pragma unroll
        for (int dc = 0; dc < 8; dc++) {
            size_t mbase = ((size_t)(b * 8 + dc) * 128 + yy) * 128;
            float m0v = (float)mq[mbase + x0c], m1v = (float)mq[mbase + x1c];
            float s = aq0[dc] * (alpha * m0v + (1.f - alpha))
                    + aq1[dc] * (alpha * m1v + (1.f - alpha));
            s += __shfl_xor(s, 1);
            vq[dc] = (_Float16)(0.25f * s);
        }
        if (ysel == 0)
            *(half8*)(outg + ((size_t)b * 4096 + i * 64 + j) * 8) = vq;
    }
}

// ---------------------------------------------------------------------------
// K3: flash attention, SPLIT=8, no max-tracking, 32 q/wave (dual-q, R8 cfg).
// V (64KB) + K (8KB) staged to LDS once; 8 key-tiles barrier-free.
// Denominator via MFMA-ones. Epilogue fuses z = ca_w1 * acc.
// Block = 8 waves x 32 q = 256 q. bid: qt=bid&15, b=(bid>>4)&bmask, s=bid>>sshift.
// ---------------------------------------------------------------------------
__global__ __launch_bounds__(512, 4) void attn_kernel(
    const _Float16* __restrict__ Qg, const _Float16* __restrict__ Kg,
    const _Float16* __restrict__ Vg, const _Float16* __restrict__ ApackCA,
    _Float16* __restrict__ pacc, float* __restrict__ pml,
    int bmask, int sshift, int bbase)
{
    __shared__ __align__(16) _Float16 Vlds[8 * 4096];
    __shared__ __align__(16) _Float16 Klds[8 * 512];
    int tid = threadIdx.x, lane = tid & 63, w = tid >> 6;
    int q = lane & 15, g = lane >> 4;
    int bid = blockIdx.x;
    int qt = bid & 15, b = bbase + ((bid >> 4) & bmask), s = bid >> sshift;

    const _Float16* Kb = Kg + ((size_t)b * 4096 + s * 512) * 8;
    const _Float16* Vbase = Vg + (size_t)b * 64 * 4096 + s * 512;

    {
        int cc = w * 8 + (lane >> 3);
        int chl = (lane & 7) ^ (cc & 7);
        const _Float16* src0 = Vbase + (size_t)cc * 4096 + chl * 8;
#pragma unroll
        for (int t = 0; t < 8; t++)
            gload16(src0 + t * 64, Vlds + t * 4096 + w * 512);
        gload16(Kb + (size_t)(w * 64 + lane) * 8, Klds + w * 512);
    }
    half8 qf0 = {}, qf1 = {};
    if (g == 0) {
        int qb = qt * 256 + w * 32 + q;
        half8 r0 = *(const half8*)(Qg + ((size_t)b * 4096 + qb) * 8);
        half8 r1 = *(const half8*)(Qg + ((size_t)b * 4096 + qb + 16) * 8);
#pragma unroll
        for (int j = 0; j < 8; j++) {
            qf0[j] = (_Float16)((float)r0[j] * 1.44269504f);
            qf1[j] = (_Float16)((float)r1[j] * 1.44269504f);
        }
    }
    __syncthreads();

    half8 ones;
#pragma unroll
    for (int j = 0; j < 8; j++) ones[j] = (_Float16)1.f;

    f32x4 acc0[4] = {}, acc1[4] = {};
    f32x4 accl0 = {}, accl1 = {};
    const f32x4 zero4 = {};

#pragma unroll 2
    for (int t = 0; t < 8; t++) {
        const _Float16* Kt = Klds + t * 512;
        half8 af0 = *(const half8*)(Kt + q * 8);
        half8 af1 = *(const half8*)(Kt + (16 + q) * 8);
        half8 af2 = *(const half8*)(Kt + (32 + q) * 8);
        half8 af3 = *(const half8*)(Kt + (48 + q) * 8);

        half8 pb00, pb01, pb10, pb11;
        {
            f32x4 s0 = mfma16(af0, qf0, zero4);
            f32x4 s1 = mfma16(af1, qf0, zero4);
            f32x4 s2 = mfma16(af2, qf0, zero4);
            f32x4 s3 = mfma16(af3, qf0, zero4);
            f32x4 e0, e1, e2, e3;
#pragma unroll
            for (int r = 0; r < 4; r++) {
                e0[r] = __builtin_amdgcn_exp2f(s0[r]);
                e1[r] = __builtin_amdgcn_exp2f(s1[r]);
                e2[r] = __builtin_amdgcn_exp2f(s2[r]);
                e3[r] = __builtin_amdgcn_exp2f(s3[r]);
            }
            pb00 = pk8(e0, e1); pb01 = pk8(e2, e3);
            accl0 = mfma16(ones, pb00, accl0);
            accl0 = mfma16(ones, pb01, accl0);
        }
        {
            f32x4 s0 = mfma16(af0, qf1, zero4);
            f32x4 s1 = mfma16(af1, qf1, zero4);
            f32x4 s2 = mfma16(af2, qf1, zero4);
            f32x4 s3 = mfma16(af3, qf1, zero4);
            f32x4 e0, e1, e2, e3;
#pragma unroll
            for (int r = 0; r < 4; r++) {
                e0[r] = __builtin_amdgcn_exp2f(s0[r]);
                e1[r] = __builtin_amdgcn_exp2f(s1[r]);
                e2[r] = __builtin_amdgcn_exp2f(s2[r]);
                e3[r] = __builtin_amdgcn_exp2f(s3[r]);
            }
            pb10 = pk8(e0, e1); pb11 = pk8(e2, e3);
            accl1 = mfma16(ones, pb10, accl1);
            accl1 = mfma16(ones, pb11, accl1);
        }
        const _Float16* Vl = Vlds + t * 4096;
        int sw = q & 7;
        __builtin_amdgcn_s_setprio(1);
#pragma unroll
        for (int mfc = 0; mfc < 4; mfc++) {
            const _Float16* vr = Vl + (mfc * 16 + q) * 64;
            half8 av0 = *(const half8*)(vr + (g ^ sw) * 8);
            half8 av1 = *(const half8*)(vr + ((4 + g) ^ sw) * 8);
            acc0[mfc] = mfma16(av0, pb00, acc0[mfc]);
            acc1[mfc] = mfma16(av0, pb10, acc1[mfc]);
            acc0[mfc] = mfma16(av1, pb01, acc0[mfc]);
            acc1[mfc] = mfma16(av1, pb11, acc1[mfc]);
        }
        __builtin_amdgcn_s_setprio(0);
    }

    half8 a3[8];
#pragma unroll
    for (int i = 0; i < 8; i++) a3[i] = *(const half8*)(ApackCA + i * 512 + lane * 8);
    {
        half8 ob0 = pk8(acc0[0], acc0[1]);
        half8 ob1 = pk8(acc0[2], acc0[3]);
        f32x4 z[4] = {};
#pragma unroll
        for (int mf2 = 0; mf2 < 4; mf2++) {
            z[mf2] = mfma16(a3[mf2], ob0, z[mf2]);
            z[mf2] = mfma16(a3[4 + mf2], ob1, z[mf2]);
        }
        size_t prow = ((size_t)bid * 256 + w * 32 + q) * 64;
#pragma unroll
        for (int mf2 = 0; mf2 < 4; mf2++)
            *(half4v*)(pacc + prow + mf2 * 16 + g * 4) = pk4(z[mf2]);
        if (g == 0) pml[bid * 256 + w * 32 + q] = accl0[0];
    }
    {
        half8 ob0 = pk8(acc1[0], acc1[1]);
        half8 ob1 = pk8(acc1[2], acc1[3]);
        f32x4 z[4] = {};
#pragma unroll
        for (int mf2 = 0; mf2 < 4; mf2++) {
            z[mf2] = mfma16(a3[mf2], ob0, z[mf2]);
            z[mf2] = mfma16(a3[4 + mf2], ob1, z[mf2]);
        }
        size_t prow = ((size_t)bid * 256 + w * 32 + 16 + q) * 64;
#pragma unroll
        for (int mf2 = 0; mf2 < 4; mf2++)
            *(half4v*)(pacc + prow + mf2 * 16 + g * 4) = pk4(z[mf2]);
        if (g == 0) pml[bid * 256 + w * 32 + 16 + q] = accl1[0];
    }
}

// ---------------------------------------------------------------------------
// K3b: elementwise combine (small-ws path only). tiles are 256-q.
// ---------------------------------------------------------------------------
__global__ __launch_bounds__(256) void combine_kernel(
    const _Float16* __restrict__ pacc, const float* __restrict__ pml,
    const float* __restrict__ cb1, _Float16* __restrict__ zb,
    int tps, int bbase)
{
    int T = blockIdx.x * 256 + threadIdx.x;
    int e = T & 7, row = T >> 3;
    int brel = row >> 12, qg = row & 4095;
    int qt16 = qg >> 8, ql = qg & 255;
    int tb0 = brel * 16 + qt16;

    float sum[8] = {};
    float L = 0.f;
    for (int s = 0; s < 8; s++) {
        int tile = s * tps + tb0;
        half8 v = *(const half8*)(pacc + ((size_t)tile * 256 + ql) * 64 + e * 8);
#pragma unroll
        for (int i = 0; i < 8; i++) sum[i] += (float)v[i];
        L += pml[tile * 256 + ql];
    }
    float inv = 1.f / L;
    half8 o;
#pragma unroll
    for (int i = 0; i < 8; i++) o[i] = (_Float16)(sum[i] * inv + cb1[e * 8 + i]);
    *(half8*)(zb + ((size_t)(bbase + brel) * 4096 + qg) * 64 + e * 8) = o;
}

// ---------------------------------------------------------------------------
// K4: out = ca_w2 * relu(upsample2x(z)) + ca_b2 + x. 512-thread blocks,
// 8 rows x 32 px; grid (4,16,4). FUSED=1: combine folded into staging.
// ---------------------------------------------------------------------------
template <int FUSED>
__global__ __launch_bounds__(512) void post_kernel(
    const _Float16* __restrict__ zg,
    const _Float16* __restrict__ pacc, const float* __restrict__ pml,
    const float* __restrict__ cb1,
    const float* __restrict__ xg,
    const _Float16* __restrict__ ApackW2K4, const float* __restrict__ cb2,
    float* __restrict__ outg)
{
    __shared__ _Float16 zt[6 * 18 * 72];
    int tid = threadIdx.x, lane = tid & 63, w = tid >> 6;
    int x0 = blockIdx.x * 32, y0 = blockIdx.y * 8, b = blockIdx.z;
    int r0 = 4 * (int)blockIdx.y - 1;
    int cbs = 16 * (int)blockIdx.x - 1;
    const _Float16* zgb = zg + (size_t)b * 4096 * 64;
    for (int idx = tid; idx < 864; idx += 512) {
        int rowi = idx >> 3, ch = idx & 7;
        int r = rowi / 18, col = rowi - r * 18;
        int zr = min(max(r0 + r, 0), 63);
        int zc = min(max(cbs + col, 0), 63);
        if constexpr (FUSED) {
            int zq = zr * 64 + zc;
            int tb = b * 16 + (zq >> 8);
            int ql = zq & 255;
            float sum[8] = {};
            float L = 0.f;
#pragma unroll
            for (int s = 0; s < 8; s++) {
                int tile = s * 64 + tb;
                half8 v = *(const half8*)(pacc + ((size_t)tile * 256 + ql) * 64 + ch * 8);
#pragma unroll
                for (int i2 = 0; i2 < 8; i2++) sum[i2] += (float)v[i2];
                L += pml[tile * 256 + ql];
            }
            float inv = 1.f / L;
            half8 o;
#pragma unroll
            for (int i2 = 0; i2 < 8; i2++) o[i2] = (_Float16)(sum[i2] * inv + cb1[ch * 8 + i2]);
            *(half8*)&zt[(r * 18 + col) * 72 + ch * 8] = o;
        } else {
            half8 v = *(const half8*)(zgb + ((size_t)(zr * 64 + zc)) * 64 + ch * 8);
            *(half8*)&zt[(r * 18 + col) * 72 + ch * 8] = v;
        }
    }
    __syncthreads();

    int q = lane & 15, g = lane >> 4;
    int y = y0 + w;
    int ra = (w >> 1) + (w & 1);
    float wyA = (w & 1) ? 0.75f : 0.25f;
    float wyB = 1.f - wyA;
    f32x4 acc[4][2] = {};
#pragma unroll
    for (int f = 0; f < 2; f++) {
        half8 a[4];
#pragma unroll
        for (int mf = 0; mf < 4; mf++)
            a[mf] = *(const half8*)(ApackW2K4 + (f * 4 + mf) * 512 + lane * 8);
#pragma unroll
        for (int nf = 0; nf < 2; nf++) {
            int pxl = nf * 16 + q;
            int ca = (pxl >> 1) + (pxl & 1);
            float wxA = (pxl & 1) ? 0.75f : 0.25f;
            float wxB = 1.f - wxA;
            half8 bfrag;
#pragma unroll
            for (int qd = 0; qd < 2; qd++) {
                int cpb = f * 32 + g * 8 + qd * 4;
                const _Float16* z00 = &zt[(ra * 18 + ca) * 72 + cpb];
                half4v h00 = *(const half4v*)z00;
                half4v h01 = *(const half4v*)(z00 + 72);
                half4v h10 = *(const half4v*)(z00 + 18 * 72);
                half4v h11 = *(const half4v*)(z00 + 18 * 72 + 72);
#pragma unroll
                for (int e = 0; e < 4; e++) {
                    float zu = ((float)h00[e] * wxA + (float)h01[e] * wxB) * wyA
                             + ((float)h10[e] * wxA + (float)h11[e] * wxB) * wyB;
                    bfrag[qd * 4 + e] = (_Float16)fmaxf(zu, 0.f);
                }
            }
#pragma unroll
            for (int mf = 0; mf < 4; mf++) acc[mf][nf] = mfma16(a[mf], bfrag, acc[mf][nf]);
        }
    }
#pragma unroll
    for (int mf = 0; mf < 4; mf++)
#pragma unroll
        for (int r = 0; r < 4; r++) {
            int c = mf * 16 + g * 4 + r;
            float bb = cb2[c];
#pragma unroll
            for (int nf = 0; nf < 2; nf++) {
                size_t oidx = ((size_t)(b * 64 + c) * 128 + y) * 128 + x0 + nf * 16 + q;
                outg[oidx] = acc[mf][nf][r] + bb + xg[oidx];
            }
        }
}

// ---------------------------------------------------------------------------
extern "C" void kernel_launch(void* const* d_in, const int* in_sizes, int n_in,
                              void* d_out, int out_size, void* d_ws, size_t ws_size,
                              hipStream_t stream)
{
    const float* x    = (const float*)d_in[0];
    const float* mask = (const float*)d_in[1];
    const float* Wq   = (const float*)d_in[2];
    const float* bq   = (const float*)d_in[3];
    const float* Wk   = (const float*)d_in[4];
    const float* bk   = (const float*)d_in[5];
    const float* Wv   = (const float*)d_in[6];
    const float* bv   = (const float*)d_in[7];
    const float* a1   = (const float*)d_in[8];
    const float* a2   = (const float*)d_in[9];
    const float* mqw1 = (const float*)d_in[10];
    const float* mqb1 = (const float*)d_in[11];
    const float* mqw2 = (const float*)d_in[12];
    const float* mqb2 = (const float*)d_in[13];
    const float* mkw1 = (const float*)d_in[14];
    const float* mkb1 = (const float*)d_in[15];
    const float* mkw2 = (const float*)d_in[16];
    const float* mkb2 = (const float*)d_in[17];
    const float* caw1 = (const float*)d_in[18];
    const float* cab1 = (const float*)d_in[19];
    const float* caw2 = (const float*)d_in[20];
    const float* cab2 = (const float*)d_in[21];

    char* ws = (char*)d_ws;
    _Float16* ApackConv = (_Float16*)(ws + WS_APCONV);
    _Float16* ApackW2s  = (_Float16*)(ws + WS_APW2S);
    _Float16* ApackCA   = (_Float16*)(ws + WS_APCA);
    _Float16* ApackW2K4 = (_Float16*)(ws + WS_APW2K4);
    _Float16* packed    = (_Float16*)(ws + WS_PACKED);
    _Float16* maskq     = (_Float16*)(ws + WS_MASKQ);
    _Float16* maskk     = (_Float16*)(ws + WS_MASKK);
    _Float16* Qg16      = (_Float16*)(ws + WS_Q16);
    _Float16* Kg16      = (_Float16*)(ws + WS_K16);
    _Float16* Vb        = (_Float16*)(ws + WS_V16);
    _Float16* zb        = (_Float16*)(ws + WS_ZB);

    prep_pack_kernel<<<dim3(64, 8, 5), dim3(256), 0, stream>>>(
        mask, mqw1, mkw1, mqw2, mkw2, caw1, caw2,
        packed, ApackConv, ApackW2s, ApackCA, ApackW2K4);
    conv_mask_kernel<<<dim3(2, 32, 8), dim3(256), 0, stream>>>(
        packed, ApackConv, ApackW2s, mqb1, mqb2, mkb1, mkb2, maskq, maskk);
    proj_kernel<<<dim3(256), dim3(512), 0, stream>>>(
        x, maskq, maskk, Wq, bq, Wk, bk, Wv, bv, a1, a2, Qg16, Kg16, Vb);

    bool big = (ws_size >= (size_t)WS_END8);
    if (big) {
        _Float16* pacc = (_Float16*)(ws + WS_PACC8);
        float*    pml  = (float*)(ws + WS_PML8);
        attn_kernel<<<dim3(512), dim3(512), 0, stream>>>(
            Qg16, Kg16, Vb, ApackCA, pacc, pml, 3, 6, 0);
        post_kernel<1><<<dim3(4, 16, 4), dim3(512), 0, stream>>>(
            zb, pacc, pml, cab1, x, ApackW2K4, cab2, (float*)d_out);
    } else {
        _Float16* pacc = (_Float16*)(ws + WS_PACC4);
        float*    pml  = (float*)(ws + WS_PML4);
        for (int bbase = 0; bbase < 4; bbase += 2) {
            attn_kernel<<<dim3(256), dim3(512), 0, stream>>>(
                Qg16, Kg16, Vb, ApackCA, pacc, pml, 1, 5, bbase);
            combine_kernel<<<dim3(256), dim3(256), 0, stream>>>(pacc, pml, cab1, zb, 32, bbase);
        }
        post_kernel<0><<<dim3(4, 16, 4), dim3(512), 0, stream>>>(
            zb, nullptr, nullptr, cab1, x, ApackW2K4, cab2, (float*)d_out);
    }
}